// Round 5
// baseline (289.802 us; speedup 1.0000x reference)
//
#include <hip/hip_runtime.h>
#include <hip/hip_cooperative_groups.h>
namespace cg = cooperative_groups;

#define H 64
#define NPB 64
#define KS 104      // bf16 elems per A-row: 64 data + xv + sv + zero-pad; 208B
typedef short bf16x8 __attribute__((ext_vector_type(8)));
typedef float f32x4 __attribute__((ext_vector_type(4)));

static __device__ __forceinline__ unsigned short f2bf(float f) {
    union { float f; unsigned u; } v; v.f = f;
    unsigned r = v.u + 0x7fffu + ((v.u >> 16) & 1u);
    return (unsigned short)(r >> 16);
}
static __device__ __forceinline__ float bf2f(unsigned short b) {
    union { unsigned u; float f; } v; v.u = ((unsigned)b) << 16;
    return v.f;
}
static __device__ __forceinline__ void split8(const float* ff, bf16x8& hi, bf16x8& lo) {
#pragma unroll
    for (int j = 0; j < 8; ++j) {
        unsigned short h = f2bf(ff[j]);
        hi[j] = (short)h;
        lo[j] = (short)f2bf(ff[j] - bf2f(h));
    }
}

// ws layout (bytes): dS [N*8] | gp [256] | Bpre [196608] | W7pre [32768]
__global__ __launch_bounds__(256, 3)
void fused_kernel(const float* __restrict__ mu, const float* __restrict__ x,
                  const int* __restrict__ ei, const float* __restrict__ ew,
                  const float* __restrict__ W1, const float* __restrict__ W2,
                  const float* __restrict__ W3, const float* __restrict__ W4,
                  const float* __restrict__ W5, const float* __restrict__ W7,
                  double* __restrict__ dS, float* __restrict__ gp,
                  bf16x8* __restrict__ Bp, bf16x8* __restrict__ W7p,
                  float* __restrict__ out, int N, int E) {
    cg::grid_group grid = cg::this_grid();
    __shared__ unsigned short Ab[2][NPB * KS];
    __shared__ float degs[NPB];
    __shared__ float red[256];
    __shared__ float v3s[256];

    const int t = threadIdx.x;
    const int bid = blockIdx.x;
    const int nb = gridDim.x;
    const int lane = t & 63;
    const int w = __builtin_amdgcn_readfirstlane(t >> 6);
    const int c = lane & 15;
    const int q = lane >> 4;
    const int hh = 16 * w + c;

    // ================= P0: zero dS + gp =================
    {
        unsigned* zb = (unsigned*)dS;
        const int zd = 2 * N;
        for (int i = bid * 256 + t; i < zd; i += nb * 256) zb[i] = 0u;
        if (bid == 0 && t < 64) gp[t] = 0.f;
    }
    grid.sync();

    // ====== P1: block 0 preps weight fragments; others do edge atomics ======
    if (bid == 0) {
        {   // v3[tl][h] = sum_k relu(W4[tl][k]) * W3[tl][h][k]
            int tl = t >> 6, h2 = t & 63;
            const float* __restrict__ w3r = W3 + (tl * H + h2) * H;
            const float* __restrict__ w4r = W4 + tl * H;
            float a0 = 0, a1 = 0, a2 = 0, a3 = 0;
#pragma unroll
            for (int k = 0; k < H; k += 4) {
                a0 += fmaxf(w4r[k + 0], 0.f) * w3r[k + 0];
                a1 += fmaxf(w4r[k + 1], 0.f) * w3r[k + 1];
                a2 += fmaxf(w4r[k + 2], 0.f) * w3r[k + 2];
                a3 += fmaxf(w4r[k + 3], 0.f) * w3r[k + 3];
            }
            v3s[t] = (a0 + a1) + (a2 + a3);
        }
        __syncthreads();
        for (int tl = 0; tl < 4; ++tl) {
            const int b3 = (tl * 4 + w) * 3;
            bf16x8 hi, lo;
#pragma unroll
            for (int s = 0; s < 2; ++s) {
                const float* __restrict__ wp = W2 + (tl * H + hh) * H + s * 32 + q * 8;
                float4 f0 = *(const float4*)(wp);
                float4 f1 = *(const float4*)(wp + 4);
                float ff[8] = {f0.x, f0.y, f0.z, f0.w, f1.x, f1.y, f1.z, f1.w};
                split8(ff, hi, lo);
                Bp[(b3 + s) * 128 + lane] = hi;
                Bp[(b3 + s) * 128 + 64 + lane] = lo;
            }
            float ff[8] = {0, 0, 0, 0, 0, 0, 0, 0};
            if (q == 0) { ff[0] = W1[tl * H + hh]; ff[1] = v3s[tl * H + hh]; }
            split8(ff, hi, lo);
            Bp[(b3 + 2) * 128 + lane] = hi;
            Bp[(b3 + 2) * 128 + 64 + lane] = lo;
        }
#pragma unroll
        for (int s = 0; s < 2; ++s) {
            const float* __restrict__ wp = W7 + hh * H + s * 32 + q * 8;
            float4 f0 = *(const float4*)(wp);
            float4 f1 = *(const float4*)(wp + 4);
            float ff[8] = {f0.x, f0.y, f0.z, f0.w, f1.x, f1.y, f1.z, f1.w};
            bf16x8 hi, lo;
            split8(ff, hi, lo);
            W7p[(w * 2 + s) * 128 + lane] = hi;
            W7p[(w * 2 + s) * 128 + 64 + lane] = lo;
        }
    } else {
        // T[n] = 4096*deg(n) + S(n), one native f64 atomic per edge
        int probe = ei[2 * (t & 63) + 1];
        bool is64 = (__ballot(probe != 0) == 0ULL);       // wave-uniform
        const int nth = (nb - 1) * 256;
        for (int e0 = 4 * ((bid - 1) * 256 + t); e0 < E; e0 += 4 * nth) {
            if (e0 + 3 < E) {
                float4 wv = *(const float4*)(ew + e0);
                int i0, i1, i2, i3;
                if (is64) {
                    int4 a = *(const int4*)(ei + 2 * (E + e0));
                    int4 b = *(const int4*)(ei + 2 * (E + e0) + 4);
                    i0 = a.x; i1 = a.z; i2 = b.x; i3 = b.z;
                } else {
                    int4 a = *(const int4*)(ei + E + e0);
                    i0 = a.x; i1 = a.y; i2 = a.z; i3 = a.w;
                }
                unsafeAtomicAdd(&dS[i0], 4096.0 + (double)wv.x);
                unsafeAtomicAdd(&dS[i1], 4096.0 + (double)wv.y);
                unsafeAtomicAdd(&dS[i2], 4096.0 + (double)wv.z);
                unsafeAtomicAdd(&dS[i3], 4096.0 + (double)wv.w);
            } else {
                for (int j = 0; j < 4 && e0 + j < E; ++j) {
                    int e = e0 + j;
                    int idx = is64 ? ei[2 * (E + e)] : ei[E + e];
                    unsafeAtomicAdd(&dS[idx], 4096.0 + (double)ew[e]);
                }
            }
        }
    }
    grid.sync();

    // ================= P2: node tiles (verified MFMA body) =================
    // zero pad cols 66..103 (dwords 33..51) once; pads never overwritten
    if (t < 128) {
        int buf = t >> 6, row = t & 63;
        unsigned* p = (unsigned*)&Ab[buf][row * KS];
#pragma unroll
        for (int d = 33; d < 52; ++d) p[d] = 0u;
    }
    const int ntiles = (N + NPB - 1) / NPB;
    for (int tile = bid; tile < ntiles; tile += nb) {
        const int base = tile * NPB;

        if (t < 64) {
            int node = base + t;
            float dg = 0.f, sv = 0.f, xv = 0.f;
            if (node < N) {
                double T = dS[node];
                double k = floor(T * (1.0 / 4096.0));
                dg = (float)k;
                sv = (float)(T - 4096.0 * k);
                xv = x[node];
            }
            degs[t] = dg;
            unsigned short xb = f2bf(xv), sb = f2bf(sv);
            Ab[0][t * KS + 64] = xb; Ab[0][t * KS + 65] = sb;
            Ab[1][t * KS + 64] = xb; Ab[1][t * KS + 65] = sb;
        }
        __syncthreads();

        {   // stage A0 = deg[m] * mu (bf16), coalesced
            const float* __restrict__ mublk = mu + (size_t)base * H;
            const int maxf = (N - base) * H;
#pragma unroll
            for (int cc = 0; cc < 4; ++cc) {
                int f = (t + 256 * cc) * 4;
                float4 v = make_float4(0.f, 0.f, 0.f, 0.f);
                if (f < maxf) v = *(const float4*)(mublk + f);
                int m = f >> 6, k = f & 63;
                float dg = degs[m];
                ushort4 b;
                b.x = f2bf(v.x * dg); b.y = f2bf(v.y * dg);
                b.z = f2bf(v.z * dg); b.w = f2bf(v.w * dg);
                *(ushort4*)(&Ab[0][m * KS + k]) = b;
            }
        }
        __syncthreads();

        unsigned short* Acur = &Ab[0][0];
        unsigned short* Anxt = &Ab[1][0];

        for (int tl = 0; tl < 4; ++tl) {
            const int b3 = (tl * 4 + w) * 3;
            bf16x8 bh0 = Bp[(b3 + 0) * 128 + lane], bl0 = Bp[(b3 + 0) * 128 + 64 + lane];
            bf16x8 bh1 = Bp[(b3 + 1) * 128 + lane], bl1 = Bp[(b3 + 1) * 128 + 64 + lane];
            bf16x8 bh2 = Bp[(b3 + 2) * 128 + lane], bl2 = Bp[(b3 + 2) * 128 + 64 + lane];

            f32x4 acc[4];
#pragma unroll
            for (int mt = 0; mt < 4; ++mt)
#pragma unroll
                for (int r = 0; r < 4; ++r) acc[mt][r] = 0.f;

#pragma unroll
            for (int mt = 0; mt < 4; ++mt) {
                const unsigned short* ar = Acur + (mt * 16 + c) * KS;
                bf16x8 a0 = *(const bf16x8*)(ar + q * 8);
                bf16x8 a1 = *(const bf16x8*)(ar + 32 + q * 8);
                bf16x8 a2 = *(const bf16x8*)(ar + 64 + q * 8);
                acc[mt] = __builtin_amdgcn_mfma_f32_16x16x32_bf16(a0, bh0, acc[mt], 0, 0, 0);
                acc[mt] = __builtin_amdgcn_mfma_f32_16x16x32_bf16(a0, bl0, acc[mt], 0, 0, 0);
                acc[mt] = __builtin_amdgcn_mfma_f32_16x16x32_bf16(a1, bh1, acc[mt], 0, 0, 0);
                acc[mt] = __builtin_amdgcn_mfma_f32_16x16x32_bf16(a1, bl1, acc[mt], 0, 0, 0);
                acc[mt] = __builtin_amdgcn_mfma_f32_16x16x32_bf16(a2, bh2, acc[mt], 0, 0, 0);
                acc[mt] = __builtin_amdgcn_mfma_f32_16x16x32_bf16(a2, bl2, acc[mt], 0, 0, 0);
            }

            const bool scale = (tl < 3);
#pragma unroll
            for (int mt = 0; mt < 4; ++mt) {
#pragma unroll
                for (int r = 0; r < 4; ++r) {
                    int m = mt * 16 + q * 4 + r;
                    float v = fmaxf(acc[mt][r], 0.f);
                    if (scale) v *= degs[m];
                    Anxt[m * KS + hh] = f2bf(v);
                }
            }
            __syncthreads();
            unsigned short* tmp = Acur; Acur = Anxt; Anxt = tmp;
        }

        {   // W7 matmul + per-node term
            bf16x8 bh0 = W7p[(w * 2 + 0) * 128 + lane], bl0 = W7p[(w * 2 + 0) * 128 + 64 + lane];
            bf16x8 bh1 = W7p[(w * 2 + 1) * 128 + lane], bl1 = W7p[(w * 2 + 1) * 128 + 64 + lane];
            f32x4 acc[4];
#pragma unroll
            for (int mt = 0; mt < 4; ++mt)
#pragma unroll
                for (int r = 0; r < 4; ++r) acc[mt][r] = 0.f;
#pragma unroll
            for (int mt = 0; mt < 4; ++mt) {
                const unsigned short* ar = Acur + (mt * 16 + c) * KS;
                bf16x8 a0 = *(const bf16x8*)(ar + q * 8);
                bf16x8 a1 = *(const bf16x8*)(ar + 32 + q * 8);
                acc[mt] = __builtin_amdgcn_mfma_f32_16x16x32_bf16(a0, bh0, acc[mt], 0, 0, 0);
                acc[mt] = __builtin_amdgcn_mfma_f32_16x16x32_bf16(a0, bl0, acc[mt], 0, 0, 0);
                acc[mt] = __builtin_amdgcn_mfma_f32_16x16x32_bf16(a1, bh1, acc[mt], 0, 0, 0);
                acc[mt] = __builtin_amdgcn_mfma_f32_16x16x32_bf16(a1, bl1, acc[mt], 0, 0, 0);
            }
            float w5v = W5[H + hh];
#pragma unroll
            for (int mt = 0; mt < 4; ++mt) {
#pragma unroll
                for (int r = 0; r < 4; ++r) {
                    float v = fmaxf(acc[mt][r], 0.f) * w5v;
                    v += __shfl_xor(v, 1);
                    v += __shfl_xor(v, 2);
                    v += __shfl_xor(v, 4);
                    v += __shfl_xor(v, 8);
                    if (c == 0) red[w * 64 + mt * 16 + q * 4 + r] = v;
                }
            }
        }
        __syncthreads();
        if (t < 64) {
            float pn = red[t] + red[64 + t] + red[128 + t] + red[192 + t];
            if (base + t < N) out[base + t] = pn;
        }
        __syncthreads();

        {   // graph pool partials from final mu
            int h2 = t & 63, mq = t >> 6;
            float s = 0.f;
#pragma unroll
            for (int i = 0; i < 16; ++i) s += bf2f(Acur[(mq * 16 + i) * KS + h2]);
            red[t] = s;
        }
        __syncthreads();
        if (t < 64) {
            float g = red[t] + red[64 + t] + red[128 + t] + red[192 + t];
            unsafeAtomicAdd(&gp[t], g);
        }
        __syncthreads();   // LDS reuse safety for next tile
    }
    grid.sync();

    // ================= P3: finalize =================
    {
        float v = fmaxf(gp[lane], 0.f) * W5[lane];
        v += __shfl_xor(v, 1);
        v += __shfl_xor(v, 2);
        v += __shfl_xor(v, 4);
        v += __shfl_xor(v, 8);
        v += __shfl_xor(v, 16);
        v += __shfl_xor(v, 32);
        for (int n = bid * 256 + t; n < N; n += nb * 256) out[n] += v;
    }
}

// ---------------------------------------------------------------------------
extern "C" void kernel_launch(void* const* d_in, const int* in_sizes, int n_in,
                              void* d_out, int out_size, void* d_ws, size_t ws_size,
                              hipStream_t stream) {
    const float* mu = (const float*)d_in[0];
    const float* x  = (const float*)d_in[1];
    const int*   ei = (const int*)d_in[2];
    const float* ew = (const float*)d_in[3];
    const float* W1 = (const float*)d_in[4];
    const float* W2 = (const float*)d_in[5];
    const float* W3 = (const float*)d_in[6];
    const float* W4 = (const float*)d_in[7];
    const float* W5 = (const float*)d_in[8];
    const float* W7 = (const float*)d_in[9];
    float* out = (float*)d_out;

    int N = in_sizes[1];
    int E = in_sizes[3];

    char* ws = (char*)d_ws;
    double* dS  = (double*)ws;
    float*  gp  = (float*)(ws + (size_t)N * 8);
    bf16x8* Bp  = (bf16x8*)(ws + (size_t)N * 8 + 256);
    bf16x8* W7p = (bf16x8*)(ws + (size_t)N * 8 + 256 + 196608);

    int maxb = 0;
    hipOccupancyMaxActiveBlocksPerMultiprocessor(&maxb, fused_kernel, 256, 0);
    if (maxb < 1) maxb = 1;
    int nb = maxb * 256;          // 256 CUs on gfx950
    if (nb > 768) nb = 768;       // 3 blocks/CU target

    void* args[] = {&mu, &x, &ei, &ew, &W1, &W2, &W3, &W4, &W5, &W7,
                    &dS, &gp, &Bp, &W7p, &out, &N, &E};
    hipLaunchCooperativeKernel((void*)fused_kernel, dim3(nb), dim3(256),
                               args, 0, stream);
}

// Round 6
// 154.532 us; speedup vs baseline: 1.8754x; 1.8754x over previous
//
#include <hip/hip_runtime.h>

#define H 64
#define NPB 64
#define KS 104      // bf16 elems per A-row: 64 data + xv + sv + zero-pad; 208B
typedef short bf16x8 __attribute__((ext_vector_type(8)));
typedef float f32x4 __attribute__((ext_vector_type(4)));

static __device__ __forceinline__ unsigned short f2bf(float f) {
    union { float f; unsigned u; } v; v.f = f;
    unsigned r = v.u + 0x7fffu + ((v.u >> 16) & 1u);
    return (unsigned short)(r >> 16);
}
static __device__ __forceinline__ float bf2f(unsigned short b) {
    union { unsigned u; float f; } v; v.u = ((unsigned)b) << 16;
    return v.f;
}
static __device__ __forceinline__ void split8(const float* ff, bf16x8& hi, bf16x8& lo) {
#pragma unroll
    for (int j = 0; j < 8; ++j) {
        unsigned short h = f2bf(ff[j]);
        hi[j] = (short)h;
        lo[j] = (short)f2bf(ff[j] - bf2f(h));
    }
}

// ws layout (bytes): dSf [N*4] | gp [256] | Bpre [196608] | W7pre [32768]
// Bpre frag index: ((tl*4+w)*3+s)*128 + hilo*64 + lane   (16B each)
// W7pre frag index: (w*2+s)*128 + hilo*64 + lane

// ---------------------------------------------------------------------------
// Block 0: build pre-split weight fragments (runs concurrently with edges).
// Blocks >=1: 8 edges/thread, ONE fp32 atomic per edge: T = 4096*deg + S.
__global__ __launch_bounds__(256)
void edge_prep_kernel(const int* __restrict__ ei, const float* __restrict__ ew,
                      const float* __restrict__ W1, const float* __restrict__ W2,
                      const float* __restrict__ W3, const float* __restrict__ W4,
                      const float* __restrict__ W7, float* __restrict__ dSf,
                      bf16x8* __restrict__ Bp, bf16x8* __restrict__ W7p, int E) {
    __shared__ float v3s[256];
    const int t = threadIdx.x;
    const int bid = blockIdx.x;

    if (bid == 0) {
        {   // v3[tl][h] = sum_k relu(W4[tl][k]) * W3[tl][h][k]
            int tl = t >> 6, h2 = t & 63;
            const float* __restrict__ w3r = W3 + (tl * H + h2) * H;
            const float* __restrict__ w4r = W4 + tl * H;
            float a0 = 0, a1 = 0, a2 = 0, a3 = 0;
#pragma unroll
            for (int k = 0; k < H; k += 4) {
                a0 += fmaxf(w4r[k + 0], 0.f) * w3r[k + 0];
                a1 += fmaxf(w4r[k + 1], 0.f) * w3r[k + 1];
                a2 += fmaxf(w4r[k + 2], 0.f) * w3r[k + 2];
                a3 += fmaxf(w4r[k + 3], 0.f) * w3r[k + 3];
            }
            v3s[t] = (a0 + a1) + (a2 + a3);
        }
        __syncthreads();
        const int w = t >> 6, lane = t & 63, c = lane & 15, q = lane >> 4;
        const int hh = 16 * w + c;
        for (int tl = 0; tl < 4; ++tl) {
            const int b3 = (tl * 4 + w) * 3;
            bf16x8 hi, lo;
#pragma unroll
            for (int s = 0; s < 2; ++s) {
                const float* __restrict__ wp = W2 + (tl * H + hh) * H + s * 32 + q * 8;
                float4 f0 = *(const float4*)(wp);
                float4 f1 = *(const float4*)(wp + 4);
                float ff[8] = {f0.x, f0.y, f0.z, f0.w, f1.x, f1.y, f1.z, f1.w};
                split8(ff, hi, lo);
                Bp[(b3 + s) * 128 + lane] = hi;
                Bp[(b3 + s) * 128 + 64 + lane] = lo;
            }
            float ff[8] = {0, 0, 0, 0, 0, 0, 0, 0};
            if (q == 0) { ff[0] = W1[tl * H + hh]; ff[1] = v3s[tl * H + hh]; }
            split8(ff, hi, lo);
            Bp[(b3 + 2) * 128 + lane] = hi;
            Bp[(b3 + 2) * 128 + 64 + lane] = lo;
        }
#pragma unroll
        for (int s = 0; s < 2; ++s) {
            const float* __restrict__ wp = W7 + hh * H + s * 32 + q * 8;
            float4 f0 = *(const float4*)(wp);
            float4 f1 = *(const float4*)(wp + 4);
            float ff[8] = {f0.x, f0.y, f0.z, f0.w, f1.x, f1.y, f1.z, f1.w};
            bf16x8 hi, lo;
            split8(ff, hi, lo);
            W7p[(w * 2 + s) * 128 + lane] = hi;
            W7p[(w * 2 + s) * 128 + 64 + lane] = lo;
        }
        return;
    }

    int probe = ei[2 * (t & 63) + 1];
    bool is64 = (__ballot(probe != 0) == 0ULL);           // wave-uniform
    const int base_e = 8 * ((bid - 1) * 256 + t);
#pragma unroll
    for (int g = 0; g < 2; ++g) {
        int e0 = base_e + 4 * g;
        if (e0 + 3 < E) {
            float4 wv = *(const float4*)(ew + e0);
            int i0, i1, i2, i3;
            if (is64) {
                int4 a = *(const int4*)(ei + 2 * (E + e0));
                int4 b = *(const int4*)(ei + 2 * (E + e0) + 4);
                i0 = a.x; i1 = a.z; i2 = b.x; i3 = b.z;
            } else {
                int4 a = *(const int4*)(ei + E + e0);
                i0 = a.x; i1 = a.y; i2 = a.z; i3 = a.w;
            }
            unsafeAtomicAdd(&dSf[i0], 4096.0f + wv.x);
            unsafeAtomicAdd(&dSf[i1], 4096.0f + wv.y);
            unsafeAtomicAdd(&dSf[i2], 4096.0f + wv.z);
            unsafeAtomicAdd(&dSf[i3], 4096.0f + wv.w);
        } else {
            for (int j = 0; j < 4 && e0 + j < E; ++j) {
                int e = e0 + j;
                int idx = is64 ? ei[2 * (E + e)] : ei[E + e];
                unsafeAtomicAdd(&dSf[idx], 4096.0f + ew[e]);
            }
        }
    }
}

// ---------------------------------------------------------------------------
__global__ __launch_bounds__(256, 4)
void node_kernel(const float* __restrict__ mu, const float* __restrict__ x,
                 const float* __restrict__ W5, const bf16x8* __restrict__ Bp,
                 const bf16x8* __restrict__ W7p, const float* __restrict__ dSf,
                 float* __restrict__ gp, float* __restrict__ out, int N) {
    __shared__ unsigned short Ab[2][NPB * KS];
    __shared__ float degs[NPB];
    __shared__ float red[4 * NPB];

    const int t = threadIdx.x;
    const int lane = t & 63;
    const int w = __builtin_amdgcn_readfirstlane(t >> 6);
    const int c = lane & 15;
    const int q = lane >> 4;
    const int hh = 16 * w + c;
    const int base = blockIdx.x * NPB;

    // zero only pad cols 66..103 (dwords 33..51) of every row, both buffers
    if (t < 128) {
        int buf = t >> 6, row = t & 63;
        unsigned* p = (unsigned*)&Ab[buf][row * KS];
#pragma unroll
        for (int d = 33; d < 52; ++d) p[d] = 0u;
    }
    // per-node scalars; xv/sv -> cols 64/65 of BOTH buffers
    if (t < 64) {
        int node = base + t;
        float dg = 0.f, sv = 0.f, xv = 0.f;
        if (node < N) {
            float T = dSf[node];
            float k = floorf(T * (1.0f / 4096.0f));
            dg = k;
            sv = T - 4096.0f * k;
            xv = x[node];
        }
        degs[t] = dg;
        unsigned short xb = f2bf(xv), sb = f2bf(sv);
        Ab[0][t * KS + 64] = xb; Ab[0][t * KS + 65] = sb;
        Ab[1][t * KS + 64] = xb; Ab[1][t * KS + 65] = sb;
    }
    __syncthreads();

    // stage A0 = deg[m] * mu (bf16), coalesced
    {
        const float* __restrict__ mublk = mu + (size_t)base * H;
        const int maxf = (N - base) * H;
#pragma unroll
        for (int cc = 0; cc < 4; ++cc) {
            int f = (t + 256 * cc) * 4;
            float4 v = make_float4(0.f, 0.f, 0.f, 0.f);
            if (f < maxf) v = *(const float4*)(mublk + f);
            int m = f >> 6, k = f & 63;
            float dg = degs[m];
            ushort4 b;
            b.x = f2bf(v.x * dg); b.y = f2bf(v.y * dg);
            b.z = f2bf(v.z * dg); b.w = f2bf(v.w * dg);
            *(ushort4*)(&Ab[0][m * KS + k]) = b;
        }
    }
    __syncthreads();

    unsigned short* Acur = &Ab[0][0];
    unsigned short* Anxt = &Ab[1][0];

    for (int tl = 0; tl < 4; ++tl) {
        const int b3 = (tl * 4 + w) * 3;
        bf16x8 bh0 = Bp[(b3 + 0) * 128 + lane], bl0 = Bp[(b3 + 0) * 128 + 64 + lane];
        bf16x8 bh1 = Bp[(b3 + 1) * 128 + lane], bl1 = Bp[(b3 + 1) * 128 + 64 + lane];
        bf16x8 bh2 = Bp[(b3 + 2) * 128 + lane], bl2 = Bp[(b3 + 2) * 128 + 64 + lane];

        f32x4 acc[4];
#pragma unroll
        for (int mt = 0; mt < 4; ++mt)
#pragma unroll
            for (int r = 0; r < 4; ++r) acc[mt][r] = 0.f;

#pragma unroll
        for (int mt = 0; mt < 4; ++mt) {
            const unsigned short* ar = Acur + (mt * 16 + c) * KS;
            bf16x8 a0 = *(const bf16x8*)(ar + q * 8);
            bf16x8 a1 = *(const bf16x8*)(ar + 32 + q * 8);
            bf16x8 a2 = *(const bf16x8*)(ar + 64 + q * 8);
            acc[mt] = __builtin_amdgcn_mfma_f32_16x16x32_bf16(a0, bh0, acc[mt], 0, 0, 0);
            acc[mt] = __builtin_amdgcn_mfma_f32_16x16x32_bf16(a0, bl0, acc[mt], 0, 0, 0);
            acc[mt] = __builtin_amdgcn_mfma_f32_16x16x32_bf16(a1, bh1, acc[mt], 0, 0, 0);
            acc[mt] = __builtin_amdgcn_mfma_f32_16x16x32_bf16(a1, bl1, acc[mt], 0, 0, 0);
            acc[mt] = __builtin_amdgcn_mfma_f32_16x16x32_bf16(a2, bh2, acc[mt], 0, 0, 0);
            acc[mt] = __builtin_amdgcn_mfma_f32_16x16x32_bf16(a2, bl2, acc[mt], 0, 0, 0);
        }

        const bool scale = (tl < 3);
#pragma unroll
        for (int mt = 0; mt < 4; ++mt) {
#pragma unroll
            for (int r = 0; r < 4; ++r) {
                int m = mt * 16 + q * 4 + r;
                float v = fmaxf(acc[mt][r], 0.f);
                if (scale) v *= degs[m];
                Anxt[m * KS + hh] = f2bf(v);
            }
        }
        __syncthreads();
        unsigned short* tmp = Acur; Acur = Anxt; Anxt = tmp;
    }

    // W7 matmul + per-node term: pn[m] = sum_h relu(mu.W7[h,:]) * W5[64+h]
    {
        bf16x8 bh0 = W7p[(w * 2 + 0) * 128 + lane], bl0 = W7p[(w * 2 + 0) * 128 + 64 + lane];
        bf16x8 bh1 = W7p[(w * 2 + 1) * 128 + lane], bl1 = W7p[(w * 2 + 1) * 128 + 64 + lane];
        f32x4 acc[4];
#pragma unroll
        for (int mt = 0; mt < 4; ++mt)
#pragma unroll
            for (int r = 0; r < 4; ++r) acc[mt][r] = 0.f;
#pragma unroll
        for (int mt = 0; mt < 4; ++mt) {
            const unsigned short* ar = Acur + (mt * 16 + c) * KS;
            bf16x8 a0 = *(const bf16x8*)(ar + q * 8);
            bf16x8 a1 = *(const bf16x8*)(ar + 32 + q * 8);
            acc[mt] = __builtin_amdgcn_mfma_f32_16x16x32_bf16(a0, bh0, acc[mt], 0, 0, 0);
            acc[mt] = __builtin_amdgcn_mfma_f32_16x16x32_bf16(a0, bl0, acc[mt], 0, 0, 0);
            acc[mt] = __builtin_amdgcn_mfma_f32_16x16x32_bf16(a1, bh1, acc[mt], 0, 0, 0);
            acc[mt] = __builtin_amdgcn_mfma_f32_16x16x32_bf16(a1, bl1, acc[mt], 0, 0, 0);
        }
        float w5v = W5[H + hh];
#pragma unroll
        for (int mt = 0; mt < 4; ++mt) {
#pragma unroll
            for (int r = 0; r < 4; ++r) {
                float v = fmaxf(acc[mt][r], 0.f) * w5v;
                v += __shfl_xor(v, 1);
                v += __shfl_xor(v, 2);
                v += __shfl_xor(v, 4);
                v += __shfl_xor(v, 8);
                if (c == 0) red[w * 64 + mt * 16 + q * 4 + r] = v;
            }
        }
    }
    __syncthreads();
    if (t < 64) {
        float pn = red[t] + red[64 + t] + red[128 + t] + red[192 + t];
        if (base + t < N) out[base + t] = pn;
    }
    __syncthreads();

    // graph pool partials from final mu
    {
        int h2 = t & 63, mq = t >> 6;
        float s = 0.f;
#pragma unroll
        for (int i = 0; i < 16; ++i) s += bf2f(Acur[(mq * 16 + i) * KS + h2]);
        red[t] = s;
    }
    __syncthreads();
    if (t < 64) {
        float g = red[t] + red[64 + t] + red[128 + t] + red[192 + t];
        unsafeAtomicAdd(&gp[t], g);
    }
}

// ---------------------------------------------------------------------------
__global__ __launch_bounds__(256)
void finalize_kernel(const float* __restrict__ gp, const float* __restrict__ W5,
                     float* __restrict__ out, int N) {
    int lane = threadIdx.x & 63;
    float v = fmaxf(gp[lane], 0.f) * W5[lane];
    v += __shfl_xor(v, 1);
    v += __shfl_xor(v, 2);
    v += __shfl_xor(v, 4);
    v += __shfl_xor(v, 8);
    v += __shfl_xor(v, 16);
    v += __shfl_xor(v, 32);
    int n = blockIdx.x * blockDim.x + threadIdx.x;
    if (n < N) out[n] += v;
}

// ---------------------------------------------------------------------------
extern "C" void kernel_launch(void* const* d_in, const int* in_sizes, int n_in,
                              void* d_out, int out_size, void* d_ws, size_t ws_size,
                              hipStream_t stream) {
    const float* mu = (const float*)d_in[0];
    const float* x  = (const float*)d_in[1];
    const int*   ei = (const int*)d_in[2];
    const float* ew = (const float*)d_in[3];
    const float* W1 = (const float*)d_in[4];
    const float* W2 = (const float*)d_in[5];
    const float* W3 = (const float*)d_in[6];
    const float* W4 = (const float*)d_in[7];
    const float* W5 = (const float*)d_in[8];
    const float* W7 = (const float*)d_in[9];
    float* out = (float*)d_out;

    const int N = in_sizes[1];
    const int E = in_sizes[3];

    char* ws = (char*)d_ws;
    float*  dSf = (float*)ws;                                   // N*4
    float*  gp  = (float*)(ws + (size_t)N * 4);                 // 256 B
    bf16x8* Bp  = (bf16x8*)(ws + (size_t)N * 4 + 256);          // <=196608 B
    bf16x8* W7p = (bf16x8*)(ws + (size_t)N * 4 + 256 + 196608); // <=32768 B

    hipMemsetAsync(ws, 0, (size_t)N * 4 + 256, stream);

    int nb_e = 1 + (E + 8 * 256 - 1) / (8 * 256);
    edge_prep_kernel<<<nb_e, 256, 0, stream>>>(ei, ew, W1, W2, W3, W4, W7,
                                               dSf, Bp, W7p, E);
    node_kernel<<<(N + NPB - 1) / NPB, 256, 0, stream>>>(mu, x, W5, Bp, W7p,
                                                         dSf, gp, out, N);
    finalize_kernel<<<(N + 255) / 256, 256, 0, stream>>>(gp, W5, out, N);
}